// Round 12
// baseline (50.513 us; speedup 1.0000x reference)
//
#include <hip/hip_runtime.h>

// Projector: out[b,k,d] = sum_l softmax_k( cos(p_k, x[b,l]) ) * x[b,l,d]
// B=4096, L=200, D=64, K=8, fp32.
// v12: k-SPLIT mapping for 4 waves/SIMD. Lane = (r=t>>4, h=(t>>3)&1, c=t&7):
// 4 rows/step (row = 4*it + r, 50 steps), lane handles only k = h*4 + j
// (j=0..3). acc 64->32 VGPR, proto hoard 64->32 VGPR => <=128 VGPR =>
// launch_bounds(64,4), grid 4096, one occupancy round at 16 waves/CU.
// All cross-lane pure-VALU DPP (xor4 verified v10; xor8 same recipe, N=8).
// Octet butterfly reduce4 (xor1/xor2 + xor4 fold); denominator = quad-sum
// + xor8 (other h-octet holds the other 4 k). Slot relabeling: acc[m] is
// logical j = (c&3)^m; epilogue 2-level butterfly over r bits.

#define LQ 200
#define DQ 64
#define KQ 8
#define NSTEP 50   // 50 * 4 rows = 200, no tail

typedef float v2f __attribute__((ext_vector_type(2)));

__device__ __forceinline__ float dppx1(float v) {   // lane ^ 1 (quad_perm [1,0,3,2])
    return __int_as_float(__builtin_amdgcn_update_dpp(0, __float_as_int(v), 0xB1, 0xF, 0xF, true));
}
__device__ __forceinline__ float dppx2(float v) {   // lane ^ 2 (quad_perm [2,3,0,1])
    return __int_as_float(__builtin_amdgcn_update_dpp(0, __float_as_int(v), 0x4E, 0xF, 0xF, true));
}
// lane ^ 4: row_shl:4 -> lanes n&4==0 (banks 0,2 mask 0x5); row_shr:4 -> banks 1,3
// (mask 0xA). HW-verified in v10.
__device__ __forceinline__ float xor4(float v) {
    int vi = __float_as_int(v);
    int r1 = __builtin_amdgcn_update_dpp(0,  vi, 0x104, 0xF, 0x5, false);  // row_shl:4
    int r  = __builtin_amdgcn_update_dpp(r1, vi, 0x114, 0xF, 0xA, false);  // row_shr:4
    return __int_as_float(r);
}
// lane ^ 8 within the 16-lane DPP row: lanes n&8==0 (banks 0,1 mask 0x3) need n+8
// -> row_shl:8; lanes n&8 (banks 2,3 mask 0xC) need n-8 -> row_shr:8.
__device__ __forceinline__ float xor8(float v) {
    int vi = __float_as_int(v);
    int r1 = __builtin_amdgcn_update_dpp(0,  vi, 0x108, 0xF, 0x3, false);  // row_shl:8
    int r  = __builtin_amdgcn_update_dpp(r1, vi, 0x118, 0xF, 0xC, false);  // row_shr:8
    return __int_as_float(r);
}
__device__ __forceinline__ float allred8(float v) { // all-reduce over octet (t&7)
    v += dppx1(v); v += dppx2(v); v += xor4(v); return v;
}
__device__ __forceinline__ v2f fma2(v2f a, v2f b, v2f c) {
    return __builtin_elementwise_fma(a, b, c);      // -> v_pk_fma_f32
}
__device__ __forceinline__ float hsum2(v2f v) { return v.x + v.y; }

// octet split-butterfly for 4 values: s[j] = chunk-partials for logical j=0..3.
// Returns the full 8-chunk reduction for j == (c&3).
__device__ __forceinline__ float reduce4(const float* s, bool b1, bool b2) {
    float T0 = (b1 ? s[1] : s[0]) + dppx1(b1 ? s[0] : s[1]);
    float T1 = (b1 ? s[3] : s[2]) + dppx1(b1 ? s[2] : s[3]);
    float K  = (b2 ? T1 : T0) + dppx2(b2 ? T0 : T1);
    return K + xor4(K);
}

struct Ctx {
    float4 pA[4], pB[4];   // proto chunks for this lane's 4 k (k = h*4 + j)
    float rnp;             // 1/||p_k|| for j = c&3
    bool b1, b2;
};

// one 4-row step: dots -> reduce4 -> softmax (den via quad-sum + xor8) -> PV
__device__ __forceinline__ void step_compute(float4 f0, float4 f1,
                                             const Ctx& cx, v2f (&acc)[4][4]) {
    v2f x0 = {f0.x, f0.y}, x1 = {f0.z, f0.w};
    v2f x2 = {f1.x, f1.y}, x3 = {f1.z, f1.w};

    float s[4];
    #pragma unroll
    for (int j = 0; j < 4; ++j) {
        v2f pa0 = {cx.pA[j].x, cx.pA[j].y}, pa1 = {cx.pA[j].z, cx.pA[j].w};
        v2f pb0 = {cx.pB[j].x, cx.pB[j].y}, pb1 = {cx.pB[j].z, cx.pB[j].w};
        s[j] = hsum2(fma2(x3, pb1, fma2(x2, pb0, fma2(x1, pa1, x0 * pa0))));
    }
    float d = reduce4(s, cx.b1, cx.b2) * cx.rnp;   // full dot * rn_p, j = c&3

    v2f q2 = fma2(x3, x3, fma2(x2, x2, fma2(x1, x1, x0 * x0)));
    float sq = allred8(hsum2(q2));                  // row sumsq (all 8 chunks)

    float e0 = __expf(d * __builtin_amdgcn_rsqf(fmaxf(sq, 1e-12f)));
    // quad gather: e_m has logical j = (c&3)^m
    float e1 = dppx1(e0);
    float e2 = dppx2(e0);
    float e3 = dppx2(e1);
    float qs  = (e0 + e1) + (e2 + e3);              // this h's 4 k
    float den = qs + xor8(qs);                      // + other h-octet's 4 k
    float rd  = __builtin_amdgcn_rcpf(den);
    float a0 = e0 * rd, a1 = e1 * rd, a2 = e2 * rd, a3 = e3 * rd;

    // PV: acc[m] += a_m * x   (slot m <-> logical j = (c&3)^m)
    {
        v2f aa = {a0, a0};
        acc[0][0] = fma2(aa, x0, acc[0][0]); acc[0][1] = fma2(aa, x1, acc[0][1]);
        acc[0][2] = fma2(aa, x2, acc[0][2]); acc[0][3] = fma2(aa, x3, acc[0][3]);
    }
    {
        v2f aa = {a1, a1};
        acc[1][0] = fma2(aa, x0, acc[1][0]); acc[1][1] = fma2(aa, x1, acc[1][1]);
        acc[1][2] = fma2(aa, x2, acc[1][2]); acc[1][3] = fma2(aa, x3, acc[1][3]);
    }
    {
        v2f aa = {a2, a2};
        acc[2][0] = fma2(aa, x0, acc[2][0]); acc[2][1] = fma2(aa, x1, acc[2][1]);
        acc[2][2] = fma2(aa, x2, acc[2][2]); acc[2][3] = fma2(aa, x3, acc[2][3]);
    }
    {
        v2f aa = {a3, a3};
        acc[3][0] = fma2(aa, x0, acc[3][0]); acc[3][1] = fma2(aa, x1, acc[3][1]);
        acc[3][2] = fma2(aa, x2, acc[3][2]); acc[3][3] = fma2(aa, x3, acc[3][3]);
    }
}

__global__ __launch_bounds__(64, 4) void projector_kernel(const float* __restrict__ x,
                                                          const float* __restrict__ proto,
                                                          float* __restrict__ out) {
    const int b = blockIdx.x;
    const int t = threadIdx.x;             // one wave
    const int c = t & 7;                   // chunk id (8 floats)
    const int h = (t >> 3) & 1;            // k-half
    const int r = t >> 4;                  // row slot 0..3

    Ctx cx;
    cx.b1 = (c & 1) != 0;
    cx.b2 = (c & 2) != 0;

    const float4* p4  = (const float4*)proto;
    const float4* xb4 = (const float4*)(x + (size_t)b * (LQ * DQ));

    // proto hoard: this lane's 4 k x chunk c (32 VGPR)
    #pragma unroll
    for (int j = 0; j < 4; ++j) {
        cx.pA[j] = p4[(h * 4 + j) * 16 + 2 * c];
        cx.pB[j] = p4[(h * 4 + j) * 16 + 2 * c + 1];
    }
    {
        float sp[4];
        #pragma unroll
        for (int j = 0; j < 4; ++j) {
            v2f a0 = {cx.pA[j].x, cx.pA[j].y}, a1 = {cx.pA[j].z, cx.pA[j].w};
            v2f b0 = {cx.pB[j].x, cx.pB[j].y}, b1v = {cx.pB[j].z, cx.pB[j].w};
            sp[j] = hsum2(fma2(b1v, b1v, fma2(b0, b0, fma2(a1, a1, a0 * a0))));
        }
        cx.rnp = __builtin_amdgcn_rsqf(fmaxf(reduce4(sp, cx.b1, cx.b2), 1e-12f));
    }

    v2f acc[4][4];
    #pragma unroll
    for (int m = 0; m < 4; ++m)
        #pragma unroll
        for (int q = 0; q < 4; ++q) acc[m][q] = (v2f){0.f, 0.f};

    const int l0 = r * 16 + 2 * c;   // float4 index within a 4-row block (64 float4)

    // depth-1.5 pipeline: two staging sets, 2 steps per loop iter
    float4 aA = xb4[l0],      aB = xb4[l0 + 1];        // step 0
    float4 bA = xb4[64 + l0], bB = xb4[64 + l0 + 1];   // step 1

    #pragma unroll 1
    for (int g = 0; g < 25; ++g) {
        int s2 = 2 * g + 2; s2 = (s2 < NSTEP) ? s2 : NSTEP - 1;
        int s3 = 2 * g + 3; s3 = (s3 < NSTEP) ? s3 : NSTEP - 1;
        {
            float4 na = xb4[s2 * 64 + l0], nb = xb4[s2 * 64 + l0 + 1];
            step_compute(aA, aB, cx, acc);
            aA = na; aB = nb;
        }
        {
            float4 na = xb4[s3 * 64 + l0], nb = xb4[s3 * 64 + l0 + 1];
            step_compute(bA, bB, cx, acc);
            bA = na; bB = nb;
        }
    }

    // ---- epilogue: butterfly over the 4 r-lanes (xor16 then xor32)
    #pragma unroll
    for (int i = 0; i < 2; ++i)
        #pragma unroll
        for (int q = 0; q < 4; ++q) {
            v2f send = (r & 1) ? acc[i][q] : acc[i + 2][q];
            v2f keep = (r & 1) ? acc[i + 2][q] : acc[i][q];
            v2f rr = {__shfl_xor(send.x, 16, 64), __shfl_xor(send.y, 16, 64)};
            acc[i][q] = keep + rr;
        }
    #pragma unroll
    for (int q = 0; q < 4; ++q) {
        v2f send = (r & 2) ? acc[0][q] : acc[1][q];
        v2f keep = (r & 2) ? acc[1][q] : acc[0][q];
        v2f rr = {__shfl_xor(send.x, 32, 64), __shfl_xor(send.y, 32, 64)};
        acc[0][q] = keep + rr;
    }

    // lane holds final out[k][8c..8c+8), k = h*4 + ((c&3) ^ m), m = 2*(r&1) + ((r>>1)&1)
    const int m = 2 * (r & 1) + ((r >> 1) & 1);
    const int k = h * 4 + ((c & 3) ^ m);
    float4* og = (float4*)(out + (size_t)b * (KQ * DQ));
    og[k * 16 + 2 * c]     = make_float4(acc[0][0].x, acc[0][0].y, acc[0][1].x, acc[0][1].y);
    og[k * 16 + 2 * c + 1] = make_float4(acc[0][2].x, acc[0][2].y, acc[0][3].x, acc[0][3].y);
}

extern "C" void kernel_launch(void* const* d_in, const int* in_sizes, int n_in,
                              void* d_out, int out_size, void* d_ws, size_t ws_size,
                              hipStream_t stream) {
    const float* x     = (const float*)d_in[0];   // [B, L, D] fp32
    const float* proto = (const float*)d_in[1];   // [K, D] fp32
    float* out = (float*)d_out;                   // [B, K, D] fp32

    const int Bn = in_sizes[0] / (LQ * DQ);       // 4096

    projector_kernel<<<Bn, 64, 0, stream>>>(x, proto, out);
}

// Round 13
// 43.080 us; speedup vs baseline: 1.1725x; 1.1725x over previous
//
#include <hip/hip_runtime.h>

// Projector: out[b,k,d] = sum_l softmax_k( cos(p_k, x[b,l]) ) * x[b,l,d]
// B=4096, L=200, D=64, K=8, fp32.
// v13 == v11 (best: 41.6us). TWO BATCHES PER WAVE (grid 2048 -> 8 waves/CU,
// one occupancy round). Batch 1's staging loads issue before batch 0's
// butterfly+store epilogue, hiding the second pipeline fill under VALU.
// One wave per batch-stream, x-stationary PV, zero LDS in the loop,
// all-VALU cross-lane (DPP xor4), packed-fp32, depth-3 pipeline.
// v12's k-split (4 waves/SIMD) REGRESSED to 50.5us: doubling step count
// doubled serial-chain instances; TLP didn't pay for per-row overhead.

#define LQ 200
#define DQ 64
#define KQ 8
#define NSTEP 25   // 25 * 8 rows = 200, no tail

typedef float v2f __attribute__((ext_vector_type(2)));

__device__ __forceinline__ float dppx1(float v) {   // lane ^ 1 (quad_perm [1,0,3,2])
    return __int_as_float(__builtin_amdgcn_update_dpp(0, __float_as_int(v), 0xB1, 0xF, 0xF, true));
}
__device__ __forceinline__ float dppx2(float v) {   // lane ^ 2 (quad_perm [2,3,0,1])
    return __int_as_float(__builtin_amdgcn_update_dpp(0, __float_as_int(v), 0x4E, 0xF, 0xF, true));
}
// lane ^ 4, pure VALU: row_shl:4 feeds lanes n&4==0 (banks 0,2, mask 0x5) with
// lane n+4; row_shr:4 feeds lanes n&4==4 (banks 1,3, mask 0xA) with lane n-4.
// (HW-verified v10/v11)
__device__ __forceinline__ float xor4(float v) {
    int vi = __float_as_int(v);
    int r1 = __builtin_amdgcn_update_dpp(0,  vi, 0x104, 0xF, 0x5, false);  // row_shl:4
    int r  = __builtin_amdgcn_update_dpp(r1, vi, 0x114, 0xF, 0xA, false);  // row_shr:4
    return __int_as_float(r);
}
__device__ __forceinline__ float allred8(float v) { // all-reduce over octet (t&7)
    v += dppx1(v); v += dppx2(v); v += xor4(v); return v;
}
__device__ __forceinline__ v2f fma2(v2f a, v2f b, v2f c) {
    return __builtin_elementwise_fma(a, b, c);      // -> v_pk_fma_f32
}
__device__ __forceinline__ float hsum2(v2f v) { return v.x + v.y; }

// split butterfly over the 8 octet-lanes: s[8] = chunk-partials for all 8 k.
// Returns the full reduction for k == (t&7). (HW-verified v3..v11)
__device__ __forceinline__ float reduce_dots(const float* s, bool b1, bool b2, bool b3) {
    float T0 = (b1 ? s[1] : s[0]) + dppx1(b1 ? s[0] : s[1]);
    float T1 = (b1 ? s[3] : s[2]) + dppx1(b1 ? s[2] : s[3]);
    float T2 = (b1 ? s[5] : s[4]) + dppx1(b1 ? s[4] : s[5]);
    float T3 = (b1 ? s[7] : s[6]) + dppx1(b1 ? s[6] : s[7]);
    float K0 = (b2 ? T1 : T0) + dppx2(b2 ? T0 : T1);
    float K1 = (b2 ? T3 : T2) + dppx2(b2 ? T2 : T3);
    return (b3 ? K1 : K0) + xor4(b3 ? K0 : K1);
}

struct Ctx {
    float4 pA[KQ], pB[KQ];
    float rnp;
    bool b1, b2, b3;
};

// one 8-row step: dots -> butterfly -> softmax -> x-stationary PV
__device__ __forceinline__ void step_compute(float4 f0, float4 f1,
                                             const Ctx& cx, v2f (&acc)[KQ][4]) {
    v2f x0 = {f0.x, f0.y}, x1 = {f0.z, f0.w};
    v2f x2 = {f1.x, f1.y}, x3 = {f1.z, f1.w};

    float s[KQ];
    #pragma unroll
    for (int k = 0; k < KQ; ++k) {
        v2f pa0 = {cx.pA[k].x, cx.pA[k].y}, pa1 = {cx.pA[k].z, cx.pA[k].w};
        v2f pb0 = {cx.pB[k].x, cx.pB[k].y}, pb1 = {cx.pB[k].z, cx.pB[k].w};
        v2f t2 = fma2(x3, pb1, fma2(x2, pb0, fma2(x1, pa1, x0 * pa0)));
        s[k] = hsum2(t2);
    }
    float d = reduce_dots(s, cx.b1, cx.b2, cx.b3) * cx.rnp;   // raw dot * rn_p, k=c

    v2f q2 = fma2(x3, x3, fma2(x2, x2, fma2(x1, x1, x0 * x0)));
    float sq = allred8(hsum2(q2));                             // row sumsq

    float e0 = __expf(d * __builtin_amdgcn_rsqf(fmaxf(sq, 1e-12f)));
    // octet all-gather: ej = e of k = c^j (3 DPP + 4 xor4, all VALU)
    float e1 = dppx1(e0);
    float e2 = dppx2(e0);
    float e3 = dppx2(e1);
    float e4 = xor4(e0);
    float e5 = xor4(e1);
    float e6 = xor4(e2);
    float e7 = xor4(e3);
    float rd = __builtin_amdgcn_rcpf(((e0 + e1) + (e2 + e3)) + ((e4 + e5) + (e6 + e7)));
    float aj[KQ] = {e0 * rd, e1 * rd, e2 * rd, e3 * rd,
                    e4 * rd, e5 * rd, e6 * rd, e7 * rd};

    #pragma unroll
    for (int j = 0; j < KQ; ++j) {
        v2f aa = {aj[j], aj[j]};
        acc[j][0] = fma2(aa, x0, acc[j][0]);
        acc[j][1] = fma2(aa, x1, acc[j][1]);
        acc[j][2] = fma2(aa, x2, acc[j][2]);
        acc[j][3] = fma2(aa, x3, acc[j][3]);
    }
}

__global__ __launch_bounds__(64, 2) void projector_kernel(const float* __restrict__ x,
                                                          const float* __restrict__ proto,
                                                          float* __restrict__ out) {
    const int bid = blockIdx.x;            // handles batches 2*bid and 2*bid+1
    const int t = threadIdx.x;             // one wave
    const int c = t & 7;                   // chunk id = this lane's k after reduce
    const int a = t >> 3;                  // row slot within each 8-row step

    Ctx cx;
    cx.b1 = (c & 1) != 0;
    cx.b2 = (c & 2) != 0;
    cx.b3 = (c & 4) != 0;

    const float4* p4 = (const float4*)proto;

    // raw-proto hoard: 8 k x chunk c (64 VGPR, loaded once, L1 broadcast)
    #pragma unroll
    for (int k = 0; k < KQ; ++k) {
        cx.pA[k] = p4[k * 16 + 2 * c];
        cx.pB[k] = p4[k * 16 + 2 * c + 1];
    }
    {
        float sp[KQ];
        #pragma unroll
        for (int k = 0; k < KQ; ++k) {
            v2f a0 = {cx.pA[k].x, cx.pA[k].y}, a1 = {cx.pA[k].z, cx.pA[k].w};
            v2f b0 = {cx.pB[k].x, cx.pB[k].y}, b1v = {cx.pB[k].z, cx.pB[k].w};
            sp[k] = hsum2(fma2(b1v, b1v, fma2(b0, b0, fma2(a1, a1, a0 * a0))));
        }
        cx.rnp = __builtin_amdgcn_rsqf(fmaxf(reduce_dots(sp, cx.b1, cx.b2, cx.b3), 1e-12f));
    }

    const int lofs = a * 16 + 2 * c;       // lane's float4 offset within a step row-block

    // prologue: fill the 4 staging sets from batch 2*bid
    const float4* xb4 = (const float4*)(x + (size_t)(2 * bid) * (LQ * DQ));
    float4 s0a = xb4[0 * 128 + lofs], s0b = xb4[0 * 128 + lofs + 1];
    float4 s1a = xb4[1 * 128 + lofs], s1b = xb4[1 * 128 + lofs + 1];
    float4 s2a = xb4[2 * 128 + lofs], s2b = xb4[2 * 128 + lofs + 1];
    float4 s3a = xb4[3 * 128 + lofs], s3b = xb4[3 * 128 + lofs + 1];

    #pragma unroll 1
    for (int half = 0; half < 2; ++half) {
        const size_t b = 2 * (size_t)bid + half;

        v2f acc[KQ][4];
        #pragma unroll
        for (int j = 0; j < KQ; ++j)
            #pragma unroll
            for (int q = 0; q < 4; ++q) acc[j][q] = (v2f){0.f, 0.f};

        // main loop: steps 0..23, depth-3 prefetch (clamped at stream end)
        #pragma unroll 1
        for (int g = 0; g < 6; ++g) {
            const int base = 4 * g;
            {
                const int sn = (base + 4 < NSTEP) ? base + 4 : NSTEP - 1;
                float4 na = xb4[sn * 128 + lofs], nb = xb4[sn * 128 + lofs + 1];
                step_compute(s0a, s0b, cx, acc);
                s0a = na; s0b = nb;
            }
            {
                const int sn = (base + 5 < NSTEP) ? base + 5 : NSTEP - 1;
                float4 na = xb4[sn * 128 + lofs], nb = xb4[sn * 128 + lofs + 1];
                step_compute(s1a, s1b, cx, acc);
                s1a = na; s1b = nb;
            }
            {
                const int sn = (base + 6 < NSTEP) ? base + 6 : NSTEP - 1;
                float4 na = xb4[sn * 128 + lofs], nb = xb4[sn * 128 + lofs + 1];
                step_compute(s2a, s2b, cx, acc);
                s2a = na; s2b = nb;
            }
            {
                const int sn = (base + 7 < NSTEP) ? base + 7 : NSTEP - 1;
                float4 na = xb4[sn * 128 + lofs], nb = xb4[sn * 128 + lofs + 1];
                step_compute(s3a, s3b, cx, acc);
                s3a = na; s3b = nb;
            }
        }
        step_compute(s0a, s0b, cx, acc);   // step 24

        // issue NEXT batch's staging loads before the epilogue butterfly,
        // so the refill latency hides under ~70 VALU instructions + store.
        if (half == 0) {
            xb4 = (const float4*)(x + (size_t)(2 * bid + 1) * (LQ * DQ));
            s0a = xb4[0 * 128 + lofs]; s0b = xb4[0 * 128 + lofs + 1];
            s1a = xb4[1 * 128 + lofs]; s1b = xb4[1 * 128 + lofs + 1];
            s2a = xb4[2 * 128 + lofs]; s2b = xb4[2 * 128 + lofs + 1];
            s3a = xb4[3 * 128 + lofs]; s3b = xb4[3 * 128 + lofs + 1];
        }

        // ---- split-butterfly reduce over row-slot bits (a)
        #pragma unroll
        for (int i = 0; i < 4; ++i)
            #pragma unroll
            for (int q = 0; q < 4; ++q) {
                v2f send = (a & 1) ? acc[i][q] : acc[i + 4][q];
                v2f keep = (a & 1) ? acc[i + 4][q] : acc[i][q];
                v2f r = {__shfl_xor(send.x, 8, 64), __shfl_xor(send.y, 8, 64)};
                acc[i][q] = keep + r;
            }
        #pragma unroll
        for (int i = 0; i < 2; ++i)
            #pragma unroll
            for (int q = 0; q < 4; ++q) {
                v2f send = (a & 2) ? acc[i][q] : acc[i + 2][q];
                v2f keep = (a & 2) ? acc[i + 2][q] : acc[i][q];
                v2f r = {__shfl_xor(send.x, 16, 64), __shfl_xor(send.y, 16, 64)};
                acc[i][q] = keep + r;
            }
        #pragma unroll
        for (int q = 0; q < 4; ++q) {
            v2f send = (a & 4) ? acc[0][q] : acc[1][q];
            v2f keep = (a & 4) ? acc[1][q] : acc[0][q];
            v2f r = {__shfl_xor(send.x, 32, 64), __shfl_xor(send.y, 32, 64)};
            acc[0][q] = keep + r;
        }

        // lane holds final out[k = c ^ bitrev3(a)][8c..8c+8)
        const int j = ((a & 1) << 2) | (a & 2) | ((a & 4) >> 2);
        const int k = c ^ j;
        float4* og = (float4*)(out + b * (KQ * DQ));
        og[k * 16 + 2 * c]     = make_float4(acc[0][0].x, acc[0][0].y, acc[0][1].x, acc[0][1].y);
        og[k * 16 + 2 * c + 1] = make_float4(acc[0][2].x, acc[0][2].y, acc[0][3].x, acc[0][3].y);
    }
}

extern "C" void kernel_launch(void* const* d_in, const int* in_sizes, int n_in,
                              void* d_out, int out_size, void* d_ws, size_t ws_size,
                              hipStream_t stream) {
    const float* x     = (const float*)d_in[0];   // [B, L, D] fp32
    const float* proto = (const float*)d_in[1];   // [K, D] fp32
    float* out = (float*)d_out;                   // [B, K, D] fp32

    const int Bn = in_sizes[0] / (LQ * DQ);       // 4096

    projector_kernel<<<Bn / 2, 64, 0, stream>>>(x, proto, out);
}